// Round 1
// baseline (20582.692 us; speedup 1.0000x reference)
//
#include <hip/hip_runtime.h>
#include <hip/hip_fp16.h>

// Wavefront-pipelined 20-layer ReLU RNN for MI355X.
// Grid: 160 blocks = 20 layers x 8 batch-slices (16 batch each). blockIdx = l*8+g
// so each layer chain (fixed g) lives on one XCD (%8 dispatch swizzle).
// Per step: D[16,256] = relu( [h_below | h_prev][16,512] x W_fused^T + bias )
// via mfma_f32_16x16x32_f16, weights held in VGPR B-fragments, h staged in LDS.
// Inter-layer: fp16 ring buffer (16 slots) in d_ws + produced-flags + consumer
// progress counters (back-pressure), agent-scope atomics + fences.

#define B_    128
#define T_    784
#define H_    256
#define L_    20
#define C_    10
#define G_    8      // batch slices
#define BM_   16     // batch per block
#define RING_ 16     // ring slots (power of 2)
#define XPAD_ 520    // LDS row stride in halves (512 + 8 pad)

typedef _Float16 v8h __attribute__((ext_vector_type(8)));
typedef float    v4f __attribute__((ext_vector_type(4)));

__global__ __launch_bounds__(256, 1)
void rnn_wavefront(const float* __restrict__ x,
                   const float* __restrict__ W_ih0,
                   const float* __restrict__ b_ih0,
                   const float* __restrict__ W_ih,
                   const float* __restrict__ b_ih,
                   const float* __restrict__ W_hh,
                   const float* __restrict__ b_hh,
                   const float* __restrict__ W_fc,
                   const float* __restrict__ b_fc,
                   float* __restrict__ out,
                   unsigned* __restrict__ flags,   // [L_][G_][T_]
                   unsigned* __restrict__ cons,    // [L_][G_]
                   _Float16* __restrict__ ring)    // [L_][G_][RING_][BM_][H_]
{
    const int l    = blockIdx.x >> 3;
    const int g    = blockIdx.x & 7;
    const int tid  = threadIdx.x;
    const int lane = tid & 63;
    const int wave = tid >> 6;
    const int quad = lane >> 4;
    const int s16  = lane & 15;
    const int nbase = wave * 64;   // each wave owns 64 output columns

    __shared__ _Float16 lX[BM_][XPAD_];  // cols 0..255: below-h, 256..511: own-h
    __shared__ float    lfc[BM_][H_];    // final hidden (layer 19 only)

    // zero LDS (h0 = 0; layer0's "below" region stays 0 forever)
    for (int i = tid; i < BM_ * XPAD_; i += 256) (&lX[0][0])[i] = (_Float16)0.f;

    // ---- load weight B-fragments into registers ----
    // B-frag for mfma_f32_16x16x32: lane holds B[k = quad*8 + i][n = lane&15]
    // W_fused[j][k]: k<256 -> W_ih (layer>=1), k>=256 -> W_hh.
    v8h wf[16][4];
#pragma unroll
    for (int kt = 0; kt < 16; ++kt) {
        const int k0 = kt * 32 + quad * 8;
#pragma unroll
        for (int nt = 0; nt < 4; ++nt) {
            const int j = nbase + nt * 16 + s16;
            v8h w;
            if (kt < 8) {
                if (l == 0) {
#pragma unroll
                    for (int i = 0; i < 8; ++i) w[i] = (_Float16)0.f;
                } else {
                    const float* src = &W_ih[(((size_t)(l - 1) * H_) + j) * H_ + k0];
#pragma unroll
                    for (int i = 0; i < 8; ++i) w[i] = (_Float16)src[i];
                }
            } else {
                const float* src = &W_hh[(((size_t)l * H_) + j) * H_ + (k0 - 256)];
#pragma unroll
                for (int i = 0; i < 8; ++i) w[i] = (_Float16)src[i];
            }
            wf[kt][nt] = w;
        }
    }

    float bias[4], w0v[4];
#pragma unroll
    for (int nt = 0; nt < 4; ++nt) {
        const int j = nbase + nt * 16 + s16;
        bias[nt] = b_hh[l * H_ + j] + ((l == 0) ? b_ih0[j] : b_ih[(l - 1) * H_ + j]);
        w0v[nt]  = (l == 0) ? W_ih0[j] : 0.f;
    }

    unsigned* myflag = flags + ((size_t)l * G_ + g) * T_;
    unsigned* upflag = flags + ((size_t)(l > 0 ? l - 1 : 0) * G_ + g) * T_;
    unsigned* mycons = cons + (l * G_ + g);
    unsigned* dncons = cons + (((l < L_ - 1) ? l + 1 : l) * G_ + g);
    _Float16* myring = ring + (((size_t)l * G_ + g) * RING_) * (BM_ * H_);
    _Float16* upring = ring + (((size_t)(l > 0 ? l - 1 : 0) * G_ + g) * RING_) * (BM_ * H_);

    __syncthreads();

    const int m_st = tid >> 4;          // staging: row
    const int c_st = (tid & 15) * 16;   // staging: col (16 halves = 32B per thread)

    for (int t = 0; t < T_; ++t) {
        // ---- acquire input from layer below ----
        if (l > 0) {
            if (tid == 0) {
                while (__hip_atomic_load(&upflag[t], __ATOMIC_ACQUIRE,
                                         __HIP_MEMORY_SCOPE_AGENT) == 0u) {
                    __builtin_amdgcn_s_sleep(1);
                }
            }
            __syncthreads();
            __builtin_amdgcn_fence(__ATOMIC_ACQUIRE, "agent");
            const _Float16* src = upring + (size_t)(t & (RING_ - 1)) * (BM_ * H_);
            const uint4* s4 = (const uint4*)(src + m_st * H_ + c_st);
            uint4 a0 = s4[0];
            uint4 a1 = s4[1];
            *(uint4*)&lX[m_st][c_st]     = a0;
            *(uint4*)&lX[m_st][c_st + 8] = a1;
            __syncthreads();
            // signal: slot t consumed (data now in LDS)
            if (tid == 0)
                __hip_atomic_store(mycons, (unsigned)(t + 1), __ATOMIC_RELEASE,
                                   __HIP_MEMORY_SCOPE_AGENT);
        }

        // ---- MFMA: acc[nt] = X[16,512] * W^T ----
        v4f acc[4];
#pragma unroll
        for (int nt = 0; nt < 4; ++nt) acc[nt] = (v4f){0.f, 0.f, 0.f, 0.f};
#pragma unroll
        for (int kt = 0; kt < 16; ++kt) {
            v8h a = *(const v8h*)&lX[s16][kt * 32 + quad * 8];
#pragma unroll
            for (int nt = 0; nt < 4; ++nt)
                acc[nt] = __builtin_amdgcn_mfma_f32_16x16x32_f16(a, wf[kt][nt], acc[nt], 0, 0, 0);
        }

        float xv[4];
        if (l == 0) {
#pragma unroll
            for (int r = 0; r < 4; ++r)
                xv[r] = x[(size_t)(g * BM_ + quad * 4 + r) * T_ + t];
        }

        __syncthreads();  // all waves done reading lX before overwriting own-h

        // ---- epilogue: bias (+ x*W_ih0 for layer0), relu, write own-h fp16 ----
        // C/D layout: lane holds D[m = quad*4 + r][n = lane&15 (+tile offset)]
#pragma unroll
        for (int nt = 0; nt < 4; ++nt) {
            const int n = nbase + nt * 16 + s16;
#pragma unroll
            for (int r = 0; r < 4; ++r) {
                float v = acc[nt][r] + bias[nt];
                if (l == 0) v += xv[r] * w0v[nt];
                v = fmaxf(v, 0.f);
                lX[quad * 4 + r][256 + n] = (_Float16)v;
                if (l == L_ - 1 && t == T_ - 1) lfc[quad * 4 + r][n] = v;
            }
        }
        __syncthreads();

        // ---- publish own-h to layer above ----
        if (l < L_ - 1) {
            if (t >= RING_) {
                if (tid == 0) {
                    while (__hip_atomic_load(dncons, __ATOMIC_ACQUIRE,
                                             __HIP_MEMORY_SCOPE_AGENT) <
                           (unsigned)(t - RING_ + 1)) {
                        __builtin_amdgcn_s_sleep(1);
                    }
                }
                __syncthreads();
            }
            _Float16* dst = myring + (size_t)(t & (RING_ - 1)) * (BM_ * H_);
            uint4 a0 = *(uint4*)&lX[m_st][256 + c_st];
            uint4 a1 = *(uint4*)&lX[m_st][256 + c_st + 8];
            uint4* d4 = (uint4*)(dst + m_st * H_ + c_st);
            d4[0] = a0;
            d4[1] = a1;
            __threadfence();
            __syncthreads();
            if (tid == 0)
                __hip_atomic_store(&myflag[t], 1u, __ATOMIC_RELEASE,
                                   __HIP_MEMORY_SCOPE_AGENT);
        }
    }

    // ---- final FC: out[b] = lfc[b] @ W_fc^T + b_fc  (layer 19 only) ----
    if (l == L_ - 1) {
        if (tid < BM_ * C_) {
            const int bl = tid / C_;
            const int c  = tid % C_;
            float sum = b_fc[c];
            for (int k = 0; k < H_; ++k) sum += lfc[bl][k] * W_fc[c * H_ + k];
            out[(size_t)(g * BM_ + bl) * C_ + c] = sum;
        }
    }
}

extern "C" void kernel_launch(void* const* d_in, const int* in_sizes, int n_in,
                              void* d_out, int out_size, void* d_ws, size_t ws_size,
                              hipStream_t stream) {
    const float* x     = (const float*)d_in[0];
    const float* W_ih0 = (const float*)d_in[1];
    const float* b_ih0 = (const float*)d_in[2];
    const float* W_ih  = (const float*)d_in[3];
    const float* b_ih  = (const float*)d_in[4];
    const float* W_hh  = (const float*)d_in[5];
    const float* b_hh  = (const float*)d_in[6];
    const float* W_fc  = (const float*)d_in[7];
    const float* b_fc  = (const float*)d_in[8];
    float* out = (float*)d_out;

    // workspace layout: [flags | cons | ring]
    const size_t flagsBytes = (size_t)L_ * G_ * T_ * sizeof(unsigned);   // 2,007,040
    const size_t consBytes  = (size_t)L_ * G_ * sizeof(unsigned);        // 640
    unsigned* flags = (unsigned*)d_ws;
    unsigned* cons  = (unsigned*)((char*)d_ws + flagsBytes);
    _Float16* ring  = (_Float16*)((char*)d_ws + flagsBytes + consBytes);

    // flags/cons must be zero each call (ws is re-poisoned before every launch)
    hipMemsetAsync(d_ws, 0, flagsBytes + consBytes, stream);

    rnn_wavefront<<<dim3(L_ * G_), dim3(256), 0, stream>>>(
        x, W_ih0, b_ih0, W_ih, b_ih, W_hh, b_hh, W_fc, b_fc,
        out, flags, cons, ring);
}

// Round 2
// 2588.017 us; speedup vs baseline: 7.9531x; 7.9531x over previous
//
#include <hip/hip_runtime.h>
#include <hip/hip_fp16.h>

// Wavefront-pipelined 20-layer ReLU RNN for MI355X — round 2.
// Change vs round 1: ALL inter-block communication uses relaxed agent-scope
// atomics (sc0/sc1 per-access, MALL-coherent, no cache flush). No agent-scope
// fences / __threadfence anywhere (those lower to full L2 buffer_inv /
// buffer_wbl2 on gfx950 -> 25us/step in round 1). Ordering of data-before-flag
// relies on __syncthreads()'s documented s_waitcnt vmcnt(0) drain before
// s_barrier. Flags replaced by monotonic per-(l,g) produced/consumed counters.

#define B_    128
#define T_    784
#define H_    256
#define L_    20
#define C_    10
#define G_    8      // batch slices
#define BM_   16     // batch rows per block
#define RING_ 16     // ring slots (power of 2)
#define XPAD_ 520    // LDS row stride in halves (512 + 8 pad)
#define RQW_  1024   // u64 words per ring slot (16*256 halves)

typedef _Float16 v8h __attribute__((ext_vector_type(8)));
typedef float    v4f __attribute__((ext_vector_type(4)));
typedef unsigned long long u64;

__global__ __launch_bounds__(256, 1)
void rnn_wavefront(const float* __restrict__ x,
                   const float* __restrict__ W_ih0,
                   const float* __restrict__ b_ih0,
                   const float* __restrict__ W_ih,
                   const float* __restrict__ b_ih,
                   const float* __restrict__ W_hh,
                   const float* __restrict__ b_hh,
                   const float* __restrict__ W_fc,
                   const float* __restrict__ b_fc,
                   float* __restrict__ out,
                   unsigned* __restrict__ prod,    // [L_][G_] monotonic produced count
                   unsigned* __restrict__ cons,    // [L_][G_] monotonic consumed count
                   u64* __restrict__ ring)         // [L_][G_][RING_][RQW_]
{
    const int l    = blockIdx.x >> 3;
    const int g    = blockIdx.x & 7;
    const int tid  = threadIdx.x;
    const int lane = tid & 63;
    const int wave = tid >> 6;
    const int quad = lane >> 4;
    const int s16  = lane & 15;
    const int nbase = wave * 64;   // each wave owns 64 output columns

    __shared__ _Float16 lX[BM_][XPAD_];  // cols 0..255: below-h, 256..511: own-h
    __shared__ float    lfc[BM_][H_];    // final hidden (layer 19 only)
    __shared__ unsigned sProdSeen;       // cached view of upstream produced count
    __shared__ unsigned sConsSeen;       // cached view of downstream consumed count

    if (tid == 0) { sProdSeen = 0u; sConsSeen = 0u; }
    // zero LDS (h0 = 0; layer0's "below" region stays 0 forever)
    for (int i = tid; i < BM_ * XPAD_; i += 256) (&lX[0][0])[i] = (_Float16)0.f;

    // ---- load weight B-fragments into registers ----
    // B-frag for mfma_f32_16x16x32: lane holds B[k = quad*8 + i][n = lane&15]
    // W_fused[j][k]: k<256 -> W_ih (layer>=1), k>=256 -> W_hh.
    v8h wf[16][4];
#pragma unroll
    for (int kt = 0; kt < 16; ++kt) {
        const int k0 = kt * 32 + quad * 8;
#pragma unroll
        for (int nt = 0; nt < 4; ++nt) {
            const int j = nbase + nt * 16 + s16;
            v8h w;
            if (kt < 8) {
                if (l == 0) {
#pragma unroll
                    for (int i = 0; i < 8; ++i) w[i] = (_Float16)0.f;
                } else {
                    const float* src = &W_ih[(((size_t)(l - 1) * H_) + j) * H_ + k0];
#pragma unroll
                    for (int i = 0; i < 8; ++i) w[i] = (_Float16)src[i];
                }
            } else {
                const float* src = &W_hh[(((size_t)l * H_) + j) * H_ + (k0 - 256)];
#pragma unroll
                for (int i = 0; i < 8; ++i) w[i] = (_Float16)src[i];
            }
            wf[kt][nt] = w;
        }
    }

    float bias[4], w0v[4];
#pragma unroll
    for (int nt = 0; nt < 4; ++nt) {
        const int j = nbase + nt * 16 + s16;
        bias[nt] = b_hh[l * H_ + j] + ((l == 0) ? b_ih0[j] : b_ih[(l - 1) * H_ + j]);
        w0v[nt]  = (l == 0) ? W_ih0[j] : 0.f;
    }

    unsigned* upprod = prod + ((l > 0 ? l - 1 : 0) * G_ + g);
    unsigned* myprod = prod + (l * G_ + g);
    unsigned* mycons = cons + (l * G_ + g);
    unsigned* dncons = cons + (((l < L_ - 1) ? l + 1 : l) * G_ + g);
    u64* myring = ring + ((size_t)(l * G_ + g) * RING_) * RQW_;
    u64* upring = ring + ((size_t)((l > 0 ? l - 1 : 0) * G_ + g) * RING_) * RQW_;

    __syncthreads();

    for (int t = 0; t < T_; ++t) {
        // ---- acquire input from layer below (MALL-coherent atomic loads) ----
        if (l > 0) {
            if (sProdSeen < (unsigned)(t + 1)) {
                if (tid == 0) {
                    unsigned p;
                    while ((p = __hip_atomic_load(upprod, __ATOMIC_RELAXED,
                                                  __HIP_MEMORY_SCOPE_AGENT)) <
                           (unsigned)(t + 1)) {
                        __builtin_amdgcn_s_sleep(1);
                    }
                    sProdSeen = p;
                }
                __syncthreads();  // B1: broadcast poll result
            }
            const u64* src = upring + (size_t)(t & (RING_ - 1)) * RQW_;
#pragma unroll
            for (int j = 0; j < 4; ++j) {
                const int k = tid + 256 * j;          // u64 index in slot
                u64 v = __hip_atomic_load((u64*)&src[k], __ATOMIC_RELAXED,
                                          __HIP_MEMORY_SCOPE_AGENT);
                *(u64*)&lX[k >> 6][(k & 63) * 4] = v;
            }
            __syncthreads();  // B2: staged data visible in LDS to all waves
            if (tid == 0)     // slot t consumed (copied out) -> producer may reuse
                __hip_atomic_store(mycons, (unsigned)(t + 1), __ATOMIC_RELAXED,
                                   __HIP_MEMORY_SCOPE_AGENT);
        }

        // ---- MFMA: acc[nt] = X[16,512] * W^T ----
        v4f acc[4];
#pragma unroll
        for (int nt = 0; nt < 4; ++nt) acc[nt] = (v4f){0.f, 0.f, 0.f, 0.f};
#pragma unroll
        for (int kt = 0; kt < 16; ++kt) {
            v8h a = *(const v8h*)&lX[s16][kt * 32 + quad * 8];
#pragma unroll
            for (int nt = 0; nt < 4; ++nt)
                acc[nt] = __builtin_amdgcn_mfma_f32_16x16x32_f16(a, wf[kt][nt], acc[nt], 0, 0, 0);
        }

        float xv[4];
        if (l == 0) {
#pragma unroll
            for (int r = 0; r < 4; ++r)
                xv[r] = x[(size_t)(g * BM_ + quad * 4 + r) * T_ + t];
        }

        __syncthreads();  // B3: all waves done reading lX before epilogue writes own-h

        // ---- epilogue: bias (+ x*W_ih0 for layer0), relu, write own-h fp16 ----
        // C/D layout: lane holds D[m = quad*4 + r][n = lane&15 (+tile offset)]
#pragma unroll
        for (int nt = 0; nt < 4; ++nt) {
            const int n = nbase + nt * 16 + s16;
#pragma unroll
            for (int r = 0; r < 4; ++r) {
                float v = acc[nt][r] + bias[nt];
                if (l == 0) v += xv[r] * w0v[nt];
                v = fmaxf(v, 0.f);
                lX[quad * 4 + r][256 + n] = (_Float16)v;
                if (l == L_ - 1 && t == T_ - 1) lfc[quad * 4 + r][n] = v;
            }
        }
        __syncthreads();  // B4: own-h complete in LDS

        // ---- publish own-h to layer above (MALL-coherent atomic stores) ----
        if (l < L_ - 1) {
            if (t >= RING_ && sConsSeen < (unsigned)(t - RING_ + 1)) {
                if (tid == 0) {
                    unsigned c;
                    while ((c = __hip_atomic_load(dncons, __ATOMIC_RELAXED,
                                                  __HIP_MEMORY_SCOPE_AGENT)) <
                           (unsigned)(t - RING_ + 1)) {
                        __builtin_amdgcn_s_sleep(1);
                    }
                    sConsSeen = c;
                }
                __syncthreads();  // rare back-pressure barrier
            }
            u64* dst = myring + (size_t)(t & (RING_ - 1)) * RQW_;
#pragma unroll
            for (int j = 0; j < 4; ++j) {
                const int k = tid + 256 * j;
                u64 v = *(const u64*)&lX[k >> 6][256 + (k & 63) * 4];
                __hip_atomic_store(&dst[k], v, __ATOMIC_RELAXED,
                                   __HIP_MEMORY_SCOPE_AGENT);
            }
            // B5: __syncthreads drains vmcnt(0) in every wave -> all write-through
            // stores are MALL-visible before tid0 bumps the produced counter.
            __syncthreads();
            if (tid == 0)
                __hip_atomic_store(myprod, (unsigned)(t + 1), __ATOMIC_RELAXED,
                                   __HIP_MEMORY_SCOPE_AGENT);
        }
    }

    // ---- final FC: out[b] = lfc[b] @ W_fc^T + b_fc  (layer 19 only) ----
    if (l == L_ - 1) {
        if (tid < BM_ * C_) {
            const int bl = tid / C_;
            const int c  = tid % C_;
            float sum = b_fc[c];
            for (int k = 0; k < H_; ++k) sum += lfc[bl][k] * W_fc[c * H_ + k];
            out[(size_t)(g * BM_ + bl) * C_ + c] = sum;
        }
    }
}

extern "C" void kernel_launch(void* const* d_in, const int* in_sizes, int n_in,
                              void* d_out, int out_size, void* d_ws, size_t ws_size,
                              hipStream_t stream) {
    const float* x     = (const float*)d_in[0];
    const float* W_ih0 = (const float*)d_in[1];
    const float* b_ih0 = (const float*)d_in[2];
    const float* W_ih  = (const float*)d_in[3];
    const float* b_ih  = (const float*)d_in[4];
    const float* W_hh  = (const float*)d_in[5];
    const float* b_hh  = (const float*)d_in[6];
    const float* W_fc  = (const float*)d_in[7];
    const float* b_fc  = (const float*)d_in[8];
    float* out = (float*)d_out;

    // workspace layout: [prod | cons | ring], counters zeroed each call
    const size_t cntBytes = (size_t)L_ * G_ * sizeof(unsigned);   // 640 B each
    unsigned* prod = (unsigned*)d_ws;
    unsigned* cons = (unsigned*)((char*)d_ws + cntBytes);
    u64* ring      = (u64*)((char*)d_ws + 2 * cntBytes);          // 8B-aligned (1280)

    hipMemsetAsync(d_ws, 0, 2 * cntBytes, stream);

    rnn_wavefront<<<dim3(L_ * G_), dim3(256), 0, stream>>>(
        x, W_ih0, b_ih0, W_ih, b_ih, W_hh, b_hh, W_fc, b_fc,
        out, prod, cons, ring);
}

// Round 3
// 1678.469 us; speedup vs baseline: 12.2628x; 1.5419x over previous
//
#include <hip/hip_runtime.h>
#include <hip/hip_fp16.h>

// Wavefront-pipelined 20-layer ReLU RNN for MI355X — round 3.
// vs round 2: communication is software-pipelined so no MALL round trip sits
// on the per-step critical path.
//  - Prefetch: slot t+1 is atomic-loaded into VGPRs during step t (producer
//    runs up to RING=16 ahead, so its flag is already set; guaranteed by a
//    one-step-deeper blocking poll whose result is broadcast by the barrier).
//  - Delayed publish: ring stores for slot t issue straight from epilogue
//    registers; the flag is published at step t+1's top barrier, whose
//    vmcnt(0) drain had a full step to complete.
//  - 2 barriers/step (was 5); own-h LDS round trip for staging eliminated.
// Transport stays relaxed agent-scope atomics (sc0 sc1, MALL-coherent, no
// cache flushes — round 2's lesson).

#define B_    128
#define T_    784
#define H_    256
#define L_    20
#define C_    10
#define G_    8      // batch slices
#define BM_   16     // batch rows per block
#define RING_ 16     // ring slots (power of 2)
#define SW_   264    // LDS row stride in halves (256 + 8; keeps 16B align, ~2-way banks)
#define RQW_  1024   // u64 words per ring slot (16*256 halves)

typedef _Float16 v8h __attribute__((ext_vector_type(8)));
typedef float    v4f __attribute__((ext_vector_type(4)));
typedef unsigned long long u64;

union U64H { u64 u; _Float16 h[4]; };

__global__ __launch_bounds__(256, 1)
void rnn_wavefront(const float* __restrict__ x,
                   const float* __restrict__ W_ih0,
                   const float* __restrict__ b_ih0,
                   const float* __restrict__ W_ih,
                   const float* __restrict__ b_ih,
                   const float* __restrict__ W_hh,
                   const float* __restrict__ b_hh,
                   const float* __restrict__ W_fc,
                   const float* __restrict__ b_fc,
                   float* __restrict__ out,
                   unsigned* __restrict__ prod,    // [L_][G_] monotonic produced count
                   unsigned* __restrict__ cons,    // [L_][G_] monotonic consumed count
                   u64* __restrict__ ring)         // [L_][G_][RING_][RQW_]
{
    const int l    = blockIdx.x >> 3;
    const int g    = blockIdx.x & 7;
    const int tid  = threadIdx.x;
    const int lane = tid & 63;
    const int wave = tid >> 6;
    const int quad = lane >> 4;
    const int s16  = lane & 15;
    const int nbase = wave * 64;   // each wave owns 64 output columns

    // X double buffer (input from below, per parity) + own-h (single buffer)
    __shared__ __align__(16) _Float16 bufX[2][BM_][SW_];
    __shared__ __align__(16) _Float16 lH[BM_][SW_];

    // zero LDS (h0 = 0; layer0's X stays 0 forever)
    for (int i = tid; i < (2 * BM_ + BM_) * SW_; i += 256)
        (&bufX[0][0][0])[i] = (_Float16)0.f;

    // ---- load weight B-fragments into registers ----
    // B-frag for mfma_f32_16x16x32: lane holds B[k = quad*8 + i][n = lane&15]
    // W_fused[j][k]: k<256 -> W_ih (layer>=1), k>=256 -> W_hh.
    v8h wf[16][4];
#pragma unroll
    for (int kt = 0; kt < 16; ++kt) {
        const int k0 = kt * 32 + quad * 8;
#pragma unroll
        for (int nt = 0; nt < 4; ++nt) {
            const int j = nbase + nt * 16 + s16;
            v8h w;
            if (kt < 8) {
                if (l == 0) {
#pragma unroll
                    for (int i = 0; i < 8; ++i) w[i] = (_Float16)0.f;
                } else {
                    const float* src = &W_ih[(((size_t)(l - 1) * H_) + j) * H_ + k0];
#pragma unroll
                    for (int i = 0; i < 8; ++i) w[i] = (_Float16)src[i];
                }
            } else {
                const float* src = &W_hh[(((size_t)l * H_) + j) * H_ + (k0 - 256)];
#pragma unroll
                for (int i = 0; i < 8; ++i) w[i] = (_Float16)src[i];
            }
            wf[kt][nt] = w;
        }
    }

    float bias[4], w0v[4];
#pragma unroll
    for (int nt = 0; nt < 4; ++nt) {
        const int j = nbase + nt * 16 + s16;
        bias[nt] = b_hh[l * H_ + j] + ((l == 0) ? b_ih0[j] : b_ih[(l - 1) * H_ + j]);
        w0v[nt]  = (l == 0) ? W_ih0[j] : 0.f;
    }

    unsigned* upprod = prod + ((l > 0 ? l - 1 : 0) * G_ + g);
    unsigned* myprod = prod + (l * G_ + g);
    unsigned* mycons = cons + (l * G_ + g);
    unsigned* dncons = cons + (((l < L_ - 1) ? l + 1 : l) * G_ + g);
    u64* myring = ring + ((size_t)(l * G_ + g) * RING_) * RQW_;
    u64* upring = ring + ((size_t)((l > 0 ? l - 1 : 0) * G_ + g) * RING_) * RQW_;

    unsigned pSeen = 0, cSeen = 0;   // tid0-private cached counter views

    // ---- prologue (l>0): blocking-acquire slot 0 into bufX[0] ----
    // Poll target 2 so that step 0's unconditional prefetch of slot 1 is safe.
    if (l > 0) {
        if (tid == 0) {
            while (pSeen < 2u) {
                pSeen = __hip_atomic_load(upprod, __ATOMIC_RELAXED,
                                          __HIP_MEMORY_SCOPE_AGENT);
                if (pSeen < 2u) __builtin_amdgcn_s_sleep(2);
            }
        }
        __syncthreads();   // broadcast the guarantee
        // thread tid owns column n=tid: 4 u64s = rows 0..15
        const u64* s0 = upring + (size_t)tid * 4;
#pragma unroll
        for (int c = 0; c < 4; ++c) {
            U64H cv;
            cv.u = __hip_atomic_load((u64*)&s0[c], __ATOMIC_RELAXED,
                                     __HIP_MEMORY_SCOPE_AGENT);
#pragma unroll
            for (int r = 0; r < 4; ++r) bufX[0][c * 4 + r][tid] = cv.h[r];
        }
    }

    for (int t = 0; t < T_; ++t) {
        // ---- B-top: vmcnt(0) drained in every wave => ring stores of slot
        // t-1 and prefetch loads of slot t are globally/locally complete.
        __syncthreads();
        if (tid == 0) {
            if (l < L_ - 1 && t > 0)
                __hip_atomic_store(myprod, (unsigned)t, __ATOMIC_RELAXED,
                                   __HIP_MEMORY_SCOPE_AGENT);   // slots 0..t-1 visible
            if (l > 0)
                __hip_atomic_store(mycons, (unsigned)(t + 1), __ATOMIC_RELAXED,
                                   __HIP_MEMORY_SCOPE_AGENT);   // slot t consumed
        }

        // ---- prefetch issue: slot t+1 -> VGPRs (safe: prod >= t+2 was
        // blocking-polled at step t-1 and broadcast by B-top) ----
        const bool doPf = (l > 0) && (t + 1 < T_);
        u64 pf[4];
        if (doPf) {
            const u64* src = upring + (size_t)((t + 1) & (RING_ - 1)) * RQW_ + (size_t)tid * 4;
#pragma unroll
            for (int c = 0; c < 4; ++c)
                pf[c] = __hip_atomic_load((u64*)&src[c], __ATOMIC_RELAXED,
                                          __HIP_MEMORY_SCOPE_AGENT);
        }

        // ---- tid0: deep polls for NEXT step's guarantees (usually cached) ----
        if (tid == 0) {
            if (l > 0 && t + 2 < T_) {
                const unsigned tgt = (unsigned)(t + 3);
                while (pSeen < tgt) {
                    pSeen = __hip_atomic_load(upprod, __ATOMIC_RELAXED,
                                              __HIP_MEMORY_SCOPE_AGENT);
                    if (pSeen < tgt) __builtin_amdgcn_s_sleep(2);
                }
            }
            if (l < L_ - 1 && t >= RING_) {
                const unsigned tgt = (unsigned)(t - (RING_ - 1));
                while (cSeen < tgt) {
                    cSeen = __hip_atomic_load(dncons, __ATOMIC_RELAXED,
                                              __HIP_MEMORY_SCOPE_AGENT);
                    if (cSeen < tgt) __builtin_amdgcn_s_sleep(2);
                }
            }
        }

        float xv[4];
        if (l == 0) {
#pragma unroll
            for (int r = 0; r < 4; ++r)
                xv[r] = x[(size_t)(g * BM_ + quad * 4 + r) * T_ + t];
        }

        // ---- MFMA: acc = [X(t) | h(t-1)] x W^T ----
        v4f acc[4];
#pragma unroll
        for (int nt = 0; nt < 4; ++nt) acc[nt] = (v4f){0.f, 0.f, 0.f, 0.f};
#pragma unroll
        for (int kt = 0; kt < 8; ++kt) {
            v8h a = *(const v8h*)&bufX[t & 1][s16][kt * 32 + quad * 8];
#pragma unroll
            for (int nt = 0; nt < 4; ++nt)
                acc[nt] = __builtin_amdgcn_mfma_f32_16x16x32_f16(a, wf[kt][nt], acc[nt], 0, 0, 0);
        }
#pragma unroll
        for (int kt = 8; kt < 16; ++kt) {
            v8h a = *(const v8h*)&lH[s16][(kt - 8) * 32 + quad * 8];
#pragma unroll
            for (int nt = 0; nt < 4; ++nt)
                acc[nt] = __builtin_amdgcn_mfma_f32_16x16x32_f16(a, wf[kt][nt], acc[nt], 0, 0, 0);
        }

        // ---- B-mid: MFMA reads of lH done; backpressure guarantee broadcast ----
        __syncthreads();

        // ---- epilogue: relu(acc + bias), write lH, ring stores from registers ----
        // C/D layout: lane holds D[m = quad*4 + r][n = nbase + nt*16 + s16]
        u64* const slot = myring + (size_t)(t & (RING_ - 1)) * RQW_;
#pragma unroll
        for (int nt = 0; nt < 4; ++nt) {
            const int n = nbase + nt * 16 + s16;
            U64H pk;
#pragma unroll
            for (int r = 0; r < 4; ++r) {
                float v = acc[nt][r] + bias[nt];
                if (l == 0) v += xv[r] * w0v[nt];
                v = fmaxf(v, 0.f);
                const _Float16 hv = (_Float16)v;
                lH[quad * 4 + r][n] = hv;
                pk.h[r] = hv;
            }
            if (l < L_ - 1)
                __hip_atomic_store(&slot[(size_t)n * 4 + quad], pk.u,
                                   __ATOMIC_RELAXED, __HIP_MEMORY_SCOPE_AGENT);
        }

        // ---- prefetch unscramble: VGPRs -> bufX[(t+1)&1] (2-way banks) ----
        if (doPf) {
#pragma unroll
            for (int c = 0; c < 4; ++c) {
                U64H cv;
                cv.u = pf[c];
#pragma unroll
                for (int r = 0; r < 4; ++r) bufX[(t + 1) & 1][c * 4 + r][tid] = cv.h[r];
            }
        }
    }

    // ---- drain final ring stores, publish last slot ----
    __syncthreads();
    if (tid == 0 && l < L_ - 1)
        __hip_atomic_store(myprod, (unsigned)T_, __ATOMIC_RELAXED,
                           __HIP_MEMORY_SCOPE_AGENT);

    // ---- final FC (layer 19): out[b] = h_T[b] @ W_fc^T + b_fc ----
    if (l == L_ - 1 && tid < BM_ * C_) {
        const int bl = tid / C_;
        const int c  = tid % C_;
        float sum = b_fc[c];
        for (int k = 0; k < H_; ++k) sum += (float)lH[bl][k] * W_fc[c * H_ + k];
        out[(size_t)(g * BM_ + bl) * C_ + c] = sum;
    }
}

extern "C" void kernel_launch(void* const* d_in, const int* in_sizes, int n_in,
                              void* d_out, int out_size, void* d_ws, size_t ws_size,
                              hipStream_t stream) {
    const float* x     = (const float*)d_in[0];
    const float* W_ih0 = (const float*)d_in[1];
    const float* b_ih0 = (const float*)d_in[2];
    const float* W_ih  = (const float*)d_in[3];
    const float* b_ih  = (const float*)d_in[4];
    const float* W_hh  = (const float*)d_in[5];
    const float* b_hh  = (const float*)d_in[6];
    const float* W_fc  = (const float*)d_in[7];
    const float* b_fc  = (const float*)d_in[8];
    float* out = (float*)d_out;

    // workspace layout: [prod | cons | ring], counters zeroed each call
    const size_t cntBytes = (size_t)L_ * G_ * sizeof(unsigned);   // 640 B each
    unsigned* prod = (unsigned*)d_ws;
    unsigned* cons = (unsigned*)((char*)d_ws + cntBytes);
    u64* ring      = (u64*)((char*)d_ws + 2 * cntBytes);          // 8B-aligned (1280)

    hipMemsetAsync(d_ws, 0, 2 * cntBytes, stream);

    rnn_wavefront<<<dim3(L_ * G_), dim3(256), 0, stream>>>(
        x, W_ih0, b_ih0, W_ih, b_ih, W_hh, b_hh, W_fc, b_fc,
        out, prod, cons, ring);
}